// Round 3
// baseline (74.050 us; speedup 1.0000x reference)
//
#include <hip/hip_runtime.h>

// Problem constants (B=64, IN=1024, UNITS=1024, BITS=8)
#define IN_F   1024
#define UNITS  1024
#define BDIM   64
#define NCH    32           // i-chunks (reduction split)
#define CHUNK  32           // IN_F / NCH
#define BG     4            // b-values per block
#define NBG    16           // BDIM / BG
// grid = NBG * NCH = 512 blocks  (ic = bid / NBG, bg = bid % NBG)

// Math: out[b,j] = relu(bias[j] + sum_i trunc(x[b,i] * K[i,j] / 256))
// Exact collapse of the reference's 4-round base-4 digit loop:
//   floor((floor(A/4)+B)/4) = floor((A+4B)/16) applied 4x, with
//   trunc odd-symmetric in sign(w) and x >= 0. All intermediates are
//   exact small integers in fp32 -> bit-exact, order-independent.

__global__ __launch_bounds__(256) void partial_kernel(
    const float* __restrict__ x, const float* __restrict__ K,
    float* __restrict__ ws)
{
    const int bid = blockIdx.x;          // 512 blocks
    const int bg = bid & (NBG - 1);      // 16 b-groups of 4
    const int ic = bid >> 4;             // 32 i-chunks of 32
    const int t  = threadIdx.x;          // 256 threads = 256 float4 j-groups (full row)
    const int b0 = bg * BG;
    const int i0 = ic * CHUNK;

    // x tile, pre-scaled by 1/256, transposed to [i][b] for float4 broadcast
    __shared__ float xs[CHUNK * BG];     // 128 floats
    if (t < CHUNK * BG) {
        const int ii = t >> 2;           // 0..31
        const int bb = t & 3;            // 0..3
        xs[ii * BG + bb] = x[(b0 + bb) * IN_F + i0 + ii] * (1.0f / 256.0f);
    }
    __syncthreads();

    float4 acc0 = make_float4(0.f, 0.f, 0.f, 0.f);
    float4 acc1 = acc0, acc2 = acc0, acc3 = acc0;

    const float4* kp = (const float4*)(K + (size_t)i0 * UNITS) + t;
#pragma unroll 4
    for (int i = 0; i < CHUNK; ++i) {
        const float4 k4 = kp[(size_t)i * (UNITS / 4)];   // coalesced dwordx4
        const float4 xv = *(const float4*)&xs[i * BG];   // wave-uniform broadcast
        acc0.x += truncf(xv.x * k4.x); acc0.y += truncf(xv.x * k4.y);
        acc0.z += truncf(xv.x * k4.z); acc0.w += truncf(xv.x * k4.w);
        acc1.x += truncf(xv.y * k4.x); acc1.y += truncf(xv.y * k4.y);
        acc1.z += truncf(xv.y * k4.z); acc1.w += truncf(xv.y * k4.w);
        acc2.x += truncf(xv.z * k4.x); acc2.y += truncf(xv.z * k4.y);
        acc2.z += truncf(xv.z * k4.z); acc2.w += truncf(xv.z * k4.w);
        acc3.x += truncf(xv.w * k4.x); acc3.y += truncf(xv.w * k4.y);
        acc3.z += truncf(xv.w * k4.z); acc3.w += truncf(xv.w * k4.w);
    }

    // partials: ws[ic][b][j], float4 stores, coalesced along j
    float4* wp = (float4*)(ws + ((size_t)ic * BDIM + b0) * UNITS) + t;
    wp[0 * (UNITS / 4)] = acc0;
    wp[1 * (UNITS / 4)] = acc1;
    wp[2 * (UNITS / 4)] = acc2;
    wp[3 * (UNITS / 4)] = acc3;
}

__global__ __launch_bounds__(128) void reduce_kernel(
    const float* __restrict__ ws, const float* __restrict__ bias,
    float* __restrict__ out)
{
    const int idx = blockIdx.x * 128 + threadIdx.x;  // 16384 float4 groups
    const int j4 = idx & 255;                        // 256 float4 per j-row
    const int b  = idx >> 8;

    const float4* p = (const float4*)ws + (size_t)b * (UNITS / 4) + j4;
    float4 s = make_float4(0.f, 0.f, 0.f, 0.f);
#pragma unroll
    for (int c = 0; c < NCH; ++c) {
        const float4 v = p[(size_t)c * BDIM * (UNITS / 4)];
        s.x += v.x; s.y += v.y; s.z += v.z; s.w += v.w;
    }
    const float4 bv = ((const float4*)bias)[j4];
    s.x = fmaxf(s.x + bv.x, 0.f);
    s.y = fmaxf(s.y + bv.y, 0.f);
    s.z = fmaxf(s.z + bv.z, 0.f);
    s.w = fmaxf(s.w + bv.w, 0.f);
    ((float4*)out)[idx] = s;
}

extern "C" void kernel_launch(void* const* d_in, const int* in_sizes, int n_in,
                              void* d_out, int out_size, void* d_ws, size_t ws_size,
                              hipStream_t stream) {
    const float* x    = (const float*)d_in[0];  // (64, 1024)
    const float* K    = (const float*)d_in[1];  // (1024, 1024)
    const float* bias = (const float*)d_in[2];  // (1024,)
    // d_in[3] = bits (always 8)
    float* out = (float*)d_out;                 // (64, 1024)
    float* ws  = (float*)d_ws;                  // uses NCH*B*UNITS*4 = 8 MB

    partial_kernel<<<NBG * NCH, 256, 0, stream>>>(x, K, ws);
    reduce_kernel<<<128, 128, 0, stream>>>(ws, bias, out);
}